// Round 15
// baseline (136.844 us; speedup 1.0000x reference)
//
#include <hip/hip_runtime.h>
#include <hip/hip_bf16.h>

#define N_TOK   16384   // B * N_PEP
#define NREC    10
#define EMB     256
#define TWO_EMB 512
#define OUTD    256
#define T_BLK   8       // tokens per block
#define THREADS 256     // 4 waves; wave w owns tokens 2w, 2w+1 in streaming phase

typedef __bf16 bf16x8 __attribute__((ext_vector_type(8)));
typedef float  f32x4  __attribute__((ext_vector_type(4)));

static __device__ __forceinline__ unsigned int f2bf_bits(float f) {
    unsigned int u = __builtin_bit_cast(unsigned int, f);
    u = (u + 0x7fffu + ((u >> 16) & 1u)) >> 16;   // RNE bf16
    return u & 0xffffu;
}
static __device__ __forceinline__ unsigned int pack2(float a, float b) {
    return f2bf_bits(a) | (f2bf_bits(b) << 16);
}
static __device__ __forceinline__ float bflo(unsigned int u) {
    return __builtin_bit_cast(float, u << 16);
}
static __device__ __forceinline__ float bfhi(unsigned int u) {
    return __builtin_bit_cast(float, u & 0xffff0000u);
}

// 64-lane sum: 4 DPP row_ror adds + 2 shuffles (validated spill-free, R8/R11).
static __device__ __forceinline__ float wave_sum(float p) {
    p += __builtin_bit_cast(float, __builtin_amdgcn_update_dpp(
             0, __builtin_bit_cast(int, p), 0x121, 0xf, 0xf, true));   // ror1
    p += __builtin_bit_cast(float, __builtin_amdgcn_update_dpp(
             0, __builtin_bit_cast(int, p), 0x122, 0xf, 0xf, true));   // ror2
    p += __builtin_bit_cast(float, __builtin_amdgcn_update_dpp(
             0, __builtin_bit_cast(int, p), 0x124, 0xf, 0xf, true));   // ror4
    p += __builtin_bit_cast(float, __builtin_amdgcn_update_dpp(
             0, __builtin_bit_cast(int, p), 0x128, 0xf, 0xf, true));   // ror8
    p += __shfl_xor(p, 16);
    p += __shfl_xor(p, 32);
    return p;
}

// ---------------- weight fragment prep (bf16, MFMA B-fragment order) ----------
// wp_frag: [16 nt][8 kt][64][8]   q GEMM    B[n=o][k=d] = Wp[n*256+k]
// wr_frag: [32 nt][8 kt][64][8]   qr GEMM   B[n=d][k=o] = Wr[k*512+n]  (transposed use)
// wv_frag: [16 nt][16 kt][64][8]  out GEMM  B[n=o][k=d] = Wv[n*512+k]
__global__ void prep_wfrag(const float* __restrict__ Wp,
                           const float* __restrict__ Wr,
                           const float* __restrict__ Wv,
                           short* __restrict__ wp_frag,
                           short* __restrict__ wr_frag,
                           short* __restrict__ wv_frag) {
    int idx = blockIdx.x * blockDim.x + threadIdx.x;   // grid covers 131072
    if (idx < 16 * 8 * 64 * 8) {
        int j = idx & 7, lane = (idx >> 3) & 63, kt = (idx >> 9) & 7, nt = idx >> 12;
        int n = nt * 16 + (lane & 15), k = kt * 32 + ((lane >> 4) << 3) + j;
        wp_frag[idx] = (short)f2bf_bits(Wp[n * EMB + k]);
    }
    if (idx < 32 * 8 * 64 * 8) {
        int j = idx & 7, lane = (idx >> 3) & 63, kt = (idx >> 9) & 7, nt = idx >> 12;
        int n = nt * 16 + (lane & 15), k = kt * 32 + ((lane >> 4) << 3) + j;
        wr_frag[idx] = (short)f2bf_bits(Wr[k * TWO_EMB + n]);
    }
    if (idx < 16 * 16 * 64 * 8) {
        int j = idx & 7, lane = (idx >> 3) & 63, kt = (idx >> 9) & 15, nt = idx >> 13;
        int n = nt * 16 + (lane & 15), k = kt * 32 + ((lane >> 4) << 3) + j;
        wv_frag[idx] = (short)f2bf_bits(Wv[n * TWO_EMB + k]);
    }
}

// B-fragment loaders (frag path or direct-from-f32 fallback)
template<int USE_FRAG>
static __device__ __forceinline__ bf16x8 load_b_rm(const short* __restrict__ frag,
                                                   const float* __restrict__ W,
                                                   int n, int k, int ld) {
    if constexpr (USE_FRAG) {
        return *reinterpret_cast<const bf16x8*>(frag);
    } else {
        const float* s = W + (long)n * ld + k;
        float4 f0 = *reinterpret_cast<const float4*>(s);
        float4 f1 = *reinterpret_cast<const float4*>(s + 4);
        uint4 t = { pack2(f0.x, f0.y), pack2(f0.z, f0.w), pack2(f1.x, f1.y), pack2(f1.z, f1.w) };
        return __builtin_bit_cast(bf16x8, t);
    }
}
template<int USE_FRAG>
static __device__ __forceinline__ bf16x8 load_b_tr(const short* __restrict__ frag,
                                                   const float* __restrict__ W,
                                                   int n, int k, int ld) {
    if constexpr (USE_FRAG) {
        return *reinterpret_cast<const bf16x8*>(frag);
    } else {
        unsigned int p[4];
        #pragma unroll
        for (int jj = 0; jj < 4; ++jj)
            p[jj] = pack2(W[(long)(k + 2 * jj) * ld + n], W[(long)(k + 2 * jj + 1) * ld + n]);
        uint4 t = { p[0], p[1], p[2], p[3] };
        return __builtin_bit_cast(bf16x8, t);
    }
}

// ---- one-pass streaming for a token: xbar = (sum e_r x_r) / (sum e_r) --------
// R11-exact: ring-4, each row loaded once, dotted, reduced (DPP), weighted,
// accumulated, discarded. Peak live ~52 VGPRs (proven spill-free).
static __device__ __forceinline__ void stream_token(
    const float* __restrict__ bp,
    const unsigned char* __restrict__ qrb,
    unsigned char* __restrict__ xz,
    int t, int lane,
    float4 s0l, float4 s0h, float4 s1l, float4 s1h,
    float4 s2l, float4 s2h, float4 s3l, float4 s3h)
{
    uint4 qw = *reinterpret_cast<const uint4*>(qrb + t * 1024 + lane * 16);
    const float qa0 = bflo(qw.x), qa1 = bfhi(qw.x), qa2 = bflo(qw.y), qa3 = bfhi(qw.y);
    const float qa4 = bflo(qw.z), qa5 = bfhi(qw.z), qa6 = bflo(qw.w), qa7 = bfhi(qw.w);
    const float C = 0.0625f * 1.4426950408889634f;   // 1/sqrt(256) * log2(e)

    float s = 0.f;
    float4 xb0 = make_float4(0.f, 0.f, 0.f, 0.f), xb1 = xb0;

    #define LD(r, sl, sh) { sl = *reinterpret_cast<const float4*>(bp + (r) * EMB); \
                            sh = *reinterpret_cast<const float4*>(bp + (r) * EMB + 4); }
    #define PROC(sl, sh) { \
        float p = qa0*(sl).x + qa1*(sl).y + qa2*(sl).z + qa3*(sl).w \
                + qa4*(sh).x + qa5*(sh).y + qa6*(sh).z + qa7*(sh).w; \
        p = wave_sum(p); \
        float e = exp2f(p * C);                      /* no-max: |logit| <~ 2 */ \
        s += e; \
        xb0.x += e*(sl).x; xb0.y += e*(sl).y; xb0.z += e*(sl).z; xb0.w += e*(sl).w; \
        xb1.x += e*(sh).x; xb1.y += e*(sh).y; xb1.z += e*(sh).z; xb1.w += e*(sh).w; }

    PROC(s0l, s0h); LD(4, s0l, s0h);
    PROC(s1l, s1h); LD(5, s1l, s1h);
    PROC(s2l, s2h); LD(6, s2l, s2h);
    PROC(s3l, s3h); LD(7, s3l, s3h);
    PROC(s0l, s0h); LD(8, s0l, s0h);
    PROC(s1l, s1h); LD(9, s1l, s1h);
    PROC(s2l, s2h);
    PROC(s3l, s3h);
    PROC(s0l, s0h);
    PROC(s1l, s1h);
    #undef LD
    #undef PROC

    const float inv = 1.f / s;
    uint4 wv4 = { pack2(xb0.x * inv, xb0.y * inv), pack2(xb0.z * inv, xb0.w * inv),
                  pack2(xb1.x * inv, xb1.y * inv), pack2(xb1.z * inv, xb1.w * inv) };
    *reinterpret_cast<uint4*>(xz + 1024 * t + ((lane * 16) ^ ((t & 7) << 4))) = wv4;
}

// ---------------- fused kernel: 256 thr / 8 tokens / 20 KB LDS ---------------
// R11 chassis at half block size -> 4 independent blocks/CU (vs 2) at the SAME
// proven register tier (256,4) = 64 arch + 64 AGPR. Uncorrelated block phases
// overlap streaming (HBM) with GEMM (MFMA/L2) statistically.
// M=16 MFMA tiles carry 8 real rows: A-reads duplicate lane&7, stores guarded.
template<int USE_FRAG>
__launch_bounds__(THREADS, 4)
__global__ void ga13_fused(const float* __restrict__ rec,
                           const float* __restrict__ pep,
                           const float* __restrict__ edge,
                           const float* __restrict__ Wp_w,
                           const float* __restrict__ Wp_b,
                           const float* __restrict__ Wr_w,
                           const float* __restrict__ Wv_w,
                           const float* __restrict__ Wv_b,
                           const short* __restrict__ wp_frag,
                           const short* __restrict__ wr_frag,
                           const short* __restrict__ wv_frag,
                           float* __restrict__ out) {
    // xz: pep bf16 tile (8 x 512B) in 1a, then xbar bf16 tile (8 x 1024B) in ph3
    __shared__ __align__(16) unsigned char xz[T_BLK * 1024];       // 8 KB
    __shared__ __align__(16) unsigned char qbf[T_BLK * 512];       // 4 KB
    __shared__ __align__(16) unsigned char qrb[T_BLK * 1024];      // 8 KB

    const int tid  = threadIdx.x;
    const int lane = tid & 63;
    const int wave = tid >> 6;            // 0..3
    const int tok0 = blockIdx.x * T_BLK;

    // ---- stage pep tile as bf16 (swizzled): 8 rows x 64 float4 ----
    #pragma unroll
    for (int it = 0; it < 2; ++it) {
        int idx = tid + it * THREADS;          // 0..511
        int row = idx >> 6, d4 = (idx & 63) << 2;
        float4 f = *reinterpret_cast<const float4*>(pep + (long)(tok0 + row) * EMB + d4);
        uint2 w = { pack2(f.x, f.y), pack2(f.z, f.w) };
        *reinterpret_cast<uint2*>(xz + 512 * row + ((d4 * 2) ^ (row << 4))) = w;
    }
    __syncthreads();                            // B1: pep tile ready

    // ---- 1a: q = pep @ Wp^T + bp  (M=8pad16,K=256,N=256; 4 nt/wave, 2 passes) ----
    #pragma unroll
    for (int pass = 0; pass < 2; ++pass) {
        f32x4 qacc[2] = {};
        #pragma unroll
        for (int kt = 0; kt < 8; ++kt) {
            int kk = kt * 32 + ((lane >> 4) << 3);
            int row = lane & 7;                 // rows 8-15 duplicate 0-7
            bf16x8 a = *reinterpret_cast<const bf16x8*>(xz + 512 * row + ((kk * 2) ^ (row << 4)));
            #pragma unroll
            for (int ntl = 0; ntl < 2; ++ntl) {
                int nt = wave * 4 + pass * 2 + ntl;
                bf16x8 b = load_b_rm<USE_FRAG>(wp_frag + ((nt * 8 + kt) * 64 + lane) * 8,
                                               Wp_w, nt * 16 + (lane & 15), kk, EMB);
                qacc[ntl] = __builtin_amdgcn_mfma_f32_16x16x32_bf16(a, b, qacc[ntl], 0, 0, 0);
            }
        }
        #pragma unroll
        for (int ntl = 0; ntl < 2; ++ntl) {
            int n = (wave * 4 + pass * 2 + ntl) * 16 + (lane & 15);
            float bias = Wp_b[n];
            #pragma unroll
            for (int i = 0; i < 4; ++i) {
                int row = ((lane >> 4) << 2) + i;
                if (row < T_BLK) {
                    float v = qacc[ntl][i] + bias;
                    *reinterpret_cast<unsigned short*>(qbf + 512 * row + ((n * 2) ^ (row << 4)))
                        = (unsigned short)f2bf_bits(v);
                }
            }
        }
    }

    // ---- issue token-A rows 0..3; they drain under the qr GEMM ----
    const float* srcA = (lane < 32) ? rec : edge;
    const int dloc = (lane * 8) & 255;
    const float* baseA = srcA + (long)(tok0 + wave * 2) * NREC * EMB + dloc;
    const float* baseB = baseA + (long)NREC * EMB;   // token A+1
    float4 a0l = *reinterpret_cast<const float4*>(baseA + 0 * EMB);
    float4 a0h = *reinterpret_cast<const float4*>(baseA + 0 * EMB + 4);
    float4 a1l = *reinterpret_cast<const float4*>(baseA + 1 * EMB);
    float4 a1h = *reinterpret_cast<const float4*>(baseA + 1 * EMB + 4);
    float4 a2l = *reinterpret_cast<const float4*>(baseA + 2 * EMB);
    float4 a2h = *reinterpret_cast<const float4*>(baseA + 2 * EMB + 4);
    float4 a3l = *reinterpret_cast<const float4*>(baseA + 3 * EMB);
    float4 a3h = *reinterpret_cast<const float4*>(baseA + 3 * EMB + 4);
    __syncthreads();                            // B2: qbf ready

    // ---- 1b: qr = q @ Wr  (M=8pad16,K=256,N=512; 8 nt/wave, 2 passes of 4) ----
    #pragma unroll
    for (int pass = 0; pass < 2; ++pass) {
        f32x4 racc[4] = {};
        #pragma unroll
        for (int kt = 0; kt < 8; ++kt) {
            int kk = kt * 32 + ((lane >> 4) << 3);
            int row = lane & 7;
            bf16x8 a = *reinterpret_cast<const bf16x8*>(qbf + 512 * row + ((kk * 2) ^ (row << 4)));
            #pragma unroll
            for (int ntl = 0; ntl < 4; ++ntl) {
                int nt = wave * 8 + pass * 4 + ntl;
                bf16x8 b = load_b_tr<USE_FRAG>(wr_frag + ((nt * 8 + kt) * 64 + lane) * 8,
                                               Wr_w, nt * 16 + (lane & 15), kk, TWO_EMB);
                racc[ntl] = __builtin_amdgcn_mfma_f32_16x16x32_bf16(a, b, racc[ntl], 0, 0, 0);
            }
        }
        #pragma unroll
        for (int ntl = 0; ntl < 4; ++ntl) {
            int n = (wave * 8 + pass * 4 + ntl) * 16 + (lane & 15);
            #pragma unroll
            for (int i = 0; i < 4; ++i) {
                int row = ((lane >> 4) << 2) + i;
                if (row < T_BLK)
                    *reinterpret_cast<unsigned short*>(qrb + row * 1024 + n * 2)
                        = (unsigned short)f2bf_bits(racc[ntl][i]);
            }
        }
    }
    __syncthreads();                            // B3: qrb ready

    // ---- streaming: token A (ring pre-issued), then token B ----
    stream_token(baseA, qrb, xz, wave * 2, lane, a0l, a0h, a1l, a1h, a2l, a2h, a3l, a3h);
    {
        float4 b0l = *reinterpret_cast<const float4*>(baseB + 0 * EMB);
        float4 b0h = *reinterpret_cast<const float4*>(baseB + 0 * EMB + 4);
        float4 b1l = *reinterpret_cast<const float4*>(baseB + 1 * EMB);
        float4 b1h = *reinterpret_cast<const float4*>(baseB + 1 * EMB + 4);
        float4 b2l = *reinterpret_cast<const float4*>(baseB + 2 * EMB);
        float4 b2h = *reinterpret_cast<const float4*>(baseB + 2 * EMB + 4);
        float4 b3l = *reinterpret_cast<const float4*>(baseB + 3 * EMB);
        float4 b3h = *reinterpret_cast<const float4*>(baseB + 3 * EMB + 4);
        stream_token(baseB, qrb, xz, wave * 2 + 1, lane, b0l, b0h, b1l, b1h, b2l, b2h, b3l, b3h);
    }
    __syncthreads();                            // B4: xbar tile ready

    // ---- ph3: out = q + Wv @ xbar + bv (M=8pad16,K=512,N=256; 4 nt/wave, 2 passes) ----
    #pragma unroll
    for (int pass = 0; pass < 2; ++pass) {
        f32x4 oacc[2] = {};
        #pragma unroll
        for (int kt = 0; kt < 16; ++kt) {
            int kk = kt * 32 + ((lane >> 4) << 3);
            int row = lane & 7;
            bf16x8 a = *reinterpret_cast<const bf16x8*>(xz + 1024 * row + ((kk * 2) ^ (row << 4)));
            #pragma unroll
            for (int ntl = 0; ntl < 2; ++ntl) {
                int nt = wave * 4 + pass * 2 + ntl;
                bf16x8 b = load_b_rm<USE_FRAG>(wv_frag + ((nt * 16 + kt) * 64 + lane) * 8,
                                               Wv_w, nt * 16 + (lane & 15), kk, TWO_EMB);
                oacc[ntl] = __builtin_amdgcn_mfma_f32_16x16x32_bf16(a, b, oacc[ntl], 0, 0, 0);
            }
        }
        #pragma unroll
        for (int ntl = 0; ntl < 2; ++ntl) {
            int n = (wave * 4 + pass * 2 + ntl) * 16 + (lane & 15);
            float bv = Wv_b[n];
            #pragma unroll
            for (int i = 0; i < 4; ++i) {
                int row = ((lane >> 4) << 2) + i;
                if (row < T_BLK) {
                    unsigned short qu = *reinterpret_cast<const unsigned short*>(
                        qbf + 512 * row + ((n * 2) ^ (row << 4)));
                    float qv = __builtin_bit_cast(float, (unsigned int)qu << 16);
                    out[(long)(tok0 + row) * OUTD + n] = qv + oacc[ntl][i] + bv;
                }
            }
        }
    }
}

extern "C" void kernel_launch(void* const* d_in, const int* in_sizes, int n_in,
                              void* d_out, int out_size, void* d_ws, size_t ws_size,
                              hipStream_t stream) {
    const float* rec  = (const float*)d_in[0];
    const float* pep  = (const float*)d_in[1];
    const float* edge = (const float*)d_in[2];
    const float* Wp_w = (const float*)d_in[3];
    const float* Wp_b = (const float*)d_in[4];
    const float* Wr_w = (const float*)d_in[5];
    // d_in[6] = Wr_b : irrelevant (softmax shift invariance)
    const float* Wv_w = (const float*)d_in[7];
    const float* Wv_b = (const float*)d_in[8];
    float* out = (float*)d_out;

    const size_t wp_elems = 16 * 8 * 64 * 8;    // 65536
    const size_t wr_elems = 32 * 8 * 64 * 8;    // 131072
    const size_t wv_elems = 16 * 16 * 64 * 8;   // 131072
    const size_t need = (wp_elems + wr_elems + wv_elems) * sizeof(short);
    short* wp_frag = (short*)d_ws;
    short* wr_frag = wp_frag + wp_elems;
    short* wv_frag = wr_frag + wr_elems;

    if (ws_size >= need) {
        prep_wfrag<<<512, 256, 0, stream>>>(Wp_w, Wr_w, Wv_w, wp_frag, wr_frag, wv_frag);
        ga13_fused<1><<<N_TOK / T_BLK, THREADS, 0, stream>>>(rec, pep, edge, Wp_w, Wp_b, Wr_w,
                                                             Wv_w, Wv_b, wp_frag, wr_frag, wv_frag, out);
    } else {
        ga13_fused<0><<<N_TOK / T_BLK, THREADS, 0, stream>>>(rec, pep, edge, Wp_w, Wp_b, Wr_w,
                                                             Wv_w, Wv_b, wp_frag, wr_frag, wv_frag, out);
    }
}

// Round 17
// 95.216 us; speedup vs baseline: 1.4372x; 1.4372x over previous
//
#include <hip/hip_runtime.h>
#include <hip/hip_bf16.h>

#define N_TOK   16384   // B * N_PEP
#define NREC    10
#define EMB     256
#define TWO_EMB 512
#define OUTD    256
#define T_BLK   16      // tokens per block
#define THREADS 512     // 8 waves; wave w owns tokens 2w, 2w+1 in streaming phase

typedef __bf16 bf16x8 __attribute__((ext_vector_type(8)));
typedef float  f32x4  __attribute__((ext_vector_type(4)));

static __device__ __forceinline__ unsigned int f2bf_bits(float f) {
    unsigned int u = __builtin_bit_cast(unsigned int, f);
    u = (u + 0x7fffu + ((u >> 16) & 1u)) >> 16;   // RNE bf16
    return u & 0xffffu;
}
static __device__ __forceinline__ unsigned int pack2(float a, float b) {
    return f2bf_bits(a) | (f2bf_bits(b) << 16);
}
static __device__ __forceinline__ float bflo(unsigned int u) {
    return __builtin_bit_cast(float, u << 16);
}
static __device__ __forceinline__ float bfhi(unsigned int u) {
    return __builtin_bit_cast(float, u & 0xffff0000u);
}

// 64-lane sum: 4 DPP row_ror adds (16-lane ring reduce at VALU latency) then
// two cross-group shuffles. Chain = 4 VALU + 2 DS (was 6 dependent DS ops).
// Validated spill-free at VGPR=64 (R8/R11).
static __device__ __forceinline__ float wave_sum(float p) {
    p += __builtin_bit_cast(float, __builtin_amdgcn_update_dpp(
             0, __builtin_bit_cast(int, p), 0x121, 0xf, 0xf, true));   // ror1
    p += __builtin_bit_cast(float, __builtin_amdgcn_update_dpp(
             0, __builtin_bit_cast(int, p), 0x122, 0xf, 0xf, true));   // ror2
    p += __builtin_bit_cast(float, __builtin_amdgcn_update_dpp(
             0, __builtin_bit_cast(int, p), 0x124, 0xf, 0xf, true));   // ror4
    p += __builtin_bit_cast(float, __builtin_amdgcn_update_dpp(
             0, __builtin_bit_cast(int, p), 0x128, 0xf, 0xf, true));   // ror8
    p += __shfl_xor(p, 16);
    p += __shfl_xor(p, 32);
    return p;
}

// ---------------- weight fragment prep (bf16, MFMA B-fragment order) ----------
// wp_frag: [16 nt][8 kt][64][8]   q GEMM    B[n=o][k=d] = Wp[n*256+k]
// wr_frag: [32 nt][8 kt][64][8]   qr GEMM   B[n=d][k=o] = Wr[k*512+n]  (transposed use)
// wv_frag: [16 nt][16 kt][64][8]  out GEMM  B[n=o][k=d] = Wv[n*512+k]
__global__ void prep_wfrag(const float* __restrict__ Wp,
                           const float* __restrict__ Wr,
                           const float* __restrict__ Wv,
                           short* __restrict__ wp_frag,
                           short* __restrict__ wr_frag,
                           short* __restrict__ wv_frag) {
    int idx = blockIdx.x * blockDim.x + threadIdx.x;   // grid covers 131072
    if (idx < 16 * 8 * 64 * 8) {
        int j = idx & 7, lane = (idx >> 3) & 63, kt = (idx >> 9) & 7, nt = idx >> 12;
        int n = nt * 16 + (lane & 15), k = kt * 32 + ((lane >> 4) << 3) + j;
        wp_frag[idx] = (short)f2bf_bits(Wp[n * EMB + k]);
    }
    if (idx < 32 * 8 * 64 * 8) {
        int j = idx & 7, lane = (idx >> 3) & 63, kt = (idx >> 9) & 7, nt = idx >> 12;
        int n = nt * 16 + (lane & 15), k = kt * 32 + ((lane >> 4) << 3) + j;
        wr_frag[idx] = (short)f2bf_bits(Wr[k * TWO_EMB + n]);
    }
    if (idx < 16 * 16 * 64 * 8) {
        int j = idx & 7, lane = (idx >> 3) & 63, kt = (idx >> 9) & 15, nt = idx >> 13;
        int n = nt * 16 + (lane & 15), k = kt * 32 + ((lane >> 4) << 3) + j;
        wv_frag[idx] = (short)f2bf_bits(Wv[n * TWO_EMB + k]);
    }
}

// B-fragment loaders (frag path or direct-from-f32 fallback)
template<int USE_FRAG>
static __device__ __forceinline__ bf16x8 load_b_rm(const short* __restrict__ frag,
                                                   const float* __restrict__ W,
                                                   int n, int k, int ld) {
    if constexpr (USE_FRAG) {
        return *reinterpret_cast<const bf16x8*>(frag);
    } else {
        const float* s = W + (long)n * ld + k;
        float4 f0 = *reinterpret_cast<const float4*>(s);
        float4 f1 = *reinterpret_cast<const float4*>(s + 4);
        uint4 t = { pack2(f0.x, f0.y), pack2(f0.z, f0.w), pack2(f1.x, f1.y), pack2(f1.z, f1.w) };
        return __builtin_bit_cast(bf16x8, t);
    }
}
template<int USE_FRAG>
static __device__ __forceinline__ bf16x8 load_b_tr(const short* __restrict__ frag,
                                                   const float* __restrict__ W,
                                                   int n, int k, int ld) {
    if constexpr (USE_FRAG) {
        return *reinterpret_cast<const bf16x8*>(frag);
    } else {
        unsigned int p[4];
        #pragma unroll
        for (int jj = 0; jj < 4; ++jj)
            p[jj] = pack2(W[(long)(k + 2 * jj) * ld + n], W[(long)(k + 2 * jj + 1) * ld + n]);
        uint4 t = { p[0], p[1], p[2], p[3] };
        return __builtin_bit_cast(bf16x8, t);
    }
}

// ---- one-pass streaming for a token: xbar = (sum e_r x_r) / (sum e_r) --------
// Normalization commutes with the value sum: each row loaded ONCE, dotted,
// reduced (DPP), weighted, accumulated, discarded. Peak live ~52 VGPRs.
static __device__ __forceinline__ void stream_token(
    const float* __restrict__ bp,            // this lane's base (token,row0,dloc)
    const unsigned char* __restrict__ qrb,
    unsigned char* __restrict__ xz,
    int t, int lane,
    float4 s0l, float4 s0h, float4 s1l, float4 s1h,
    float4 s2l, float4 s2h, float4 s3l, float4 s3h)   // rows 0..3 in flight
{
    uint4 qw = *reinterpret_cast<const uint4*>(qrb + t * 1024 + lane * 16);
    const float qa0 = bflo(qw.x), qa1 = bfhi(qw.x), qa2 = bflo(qw.y), qa3 = bfhi(qw.y);
    const float qa4 = bflo(qw.z), qa5 = bfhi(qw.z), qa6 = bflo(qw.w), qa7 = bfhi(qw.w);
    const float C = 0.0625f * 1.4426950408889634f;   // 1/sqrt(256) * log2(e)

    float s = 0.f;
    float4 xb0 = make_float4(0.f, 0.f, 0.f, 0.f), xb1 = xb0;

    #define LD(r, sl, sh) { sl = *reinterpret_cast<const float4*>(bp + (r) * EMB); \
                            sh = *reinterpret_cast<const float4*>(bp + (r) * EMB + 4); }
    #define PROC(sl, sh) { \
        float p = qa0*(sl).x + qa1*(sl).y + qa2*(sl).z + qa3*(sl).w \
                + qa4*(sh).x + qa5*(sh).y + qa6*(sh).z + qa7*(sh).w; \
        p = wave_sum(p); \
        float e = exp2f(p * C);                      /* no-max: |logit| <~ 2 */ \
        s += e; \
        xb0.x += e*(sl).x; xb0.y += e*(sl).y; xb0.z += e*(sl).z; xb0.w += e*(sl).w; \
        xb1.x += e*(sh).x; xb1.y += e*(sh).y; xb1.z += e*(sh).z; xb1.w += e*(sh).w; }

    PROC(s0l, s0h); LD(4, s0l, s0h);
    PROC(s1l, s1h); LD(5, s1l, s1h);
    PROC(s2l, s2h); LD(6, s2l, s2h);
    PROC(s3l, s3h); LD(7, s3l, s3h);
    PROC(s0l, s0h); LD(8, s0l, s0h);
    PROC(s1l, s1h); LD(9, s1l, s1h);
    PROC(s2l, s2h);
    PROC(s3l, s3h);
    PROC(s0l, s0h);
    PROC(s1l, s1h);
    #undef LD
    #undef PROC

    const float inv = 1.f / s;
    uint4 wv4 = { pack2(xb0.x * inv, xb0.y * inv), pack2(xb0.z * inv, xb0.w * inv),
                  pack2(xb1.x * inv, xb1.y * inv), pack2(xb1.z * inv, xb1.w * inv) };
    *reinterpret_cast<uint4*>(xz + 1024 * t + ((lane * 16) ^ ((t & 7) << 4))) = wv4;
}

// ---------------- fused kernel (commuted-projection formulation) --------------
// per token t:  q  = Wp@pep + bp                      (MFMA; kept in qbf as bf16)
//               qr = Wr^T q                           (MFMA; Wr_b drops: softmax shift-inv)
//               e_r = exp((qr . x_r)/16)              (streamed f32, one pass)
//               xbar = (sum e_r x_r) / (sum e_r)
//               out = q + Wv@xbar + bv                (MFMA; sum(attn)=1 folds bias)
template<int USE_FRAG>
__launch_bounds__(THREADS, 4)
__global__ void ga9_fused(const float* __restrict__ rec,
                          const float* __restrict__ pep,
                          const float* __restrict__ edge,
                          const float* __restrict__ Wp_w,
                          const float* __restrict__ Wp_b,
                          const float* __restrict__ Wr_w,
                          const float* __restrict__ Wv_w,
                          const float* __restrict__ Wv_b,
                          const short* __restrict__ wp_frag,
                          const short* __restrict__ wr_frag,
                          const short* __restrict__ wv_frag,
                          float* __restrict__ out) {
    // xz: pep bf16 A-tile (512B rows) in 1a, then xbar bf16 A-tile (1024B rows) in ph3
    __shared__ __align__(16) unsigned char xz[T_BLK * 1024];       // 16 KB
    __shared__ __align__(16) unsigned char qbf[T_BLK * 512];       // 8 KB (q bf16 A-tile)
    __shared__ __align__(16) unsigned char qrb[T_BLK * 1024];      // 16 KB (qr bf16 [t][512])

    const int tid  = threadIdx.x;
    const int lane = tid & 63;
    const int wave = tid >> 6;
    const int tok0 = blockIdx.x * T_BLK;

    // ---- stage pep tile as bf16 (swizzled) ----
    #pragma unroll
    for (int it = 0; it < 2; ++it) {
        int idx = tid + it * THREADS;          // 16 rows x 64 float4
        int row = idx >> 6, d4 = (idx & 63) << 2;
        float4 f = *reinterpret_cast<const float4*>(pep + (long)(tok0 + row) * EMB + d4);
        uint2 w = { pack2(f.x, f.y), pack2(f.z, f.w) };
        *reinterpret_cast<uint2*>(xz + 512 * row + ((d4 * 2) ^ ((row & 7) << 4))) = w;
    }
    __syncthreads();                            // B1: pep tile ready

    // ---- 1a: q = pep @ Wp^T + bp  (M=16,K=256,N=256; 2 n-tiles/wave) ----
    {
        f32x4 qacc[2] = {};
        #pragma unroll
        for (int kt = 0; kt < 8; ++kt) {
            int kk = kt * 32 + ((lane >> 4) << 3);
            int row = lane & 15;
            bf16x8 a = *reinterpret_cast<const bf16x8*>(xz + 512 * row + ((kk * 2) ^ ((row & 7) << 4)));
            #pragma unroll
            for (int ntl = 0; ntl < 2; ++ntl) {
                int nt = wave * 2 + ntl;
                bf16x8 b = load_b_rm<USE_FRAG>(wp_frag + ((nt * 8 + kt) * 64 + lane) * 8,
                                               Wp_w, nt * 16 + (lane & 15), kk, EMB);
                qacc[ntl] = __builtin_amdgcn_mfma_f32_16x16x32_bf16(a, b, qacc[ntl], 0, 0, 0);
            }
        }
        #pragma unroll
        for (int ntl = 0; ntl < 2; ++ntl) {
            int n = (wave * 2 + ntl) * 16 + (lane & 15);
            float bias = Wp_b[n];
            #pragma unroll
            for (int i = 0; i < 4; ++i) {
                int row = ((lane >> 4) << 2) + i;
                float v = qacc[ntl][i] + bias;
                *reinterpret_cast<unsigned short*>(qbf + 512 * row + ((n * 2) ^ ((row & 7) << 4)))
                    = (unsigned short)f2bf_bits(v);
            }
        }
    }

    // ---- issue token-A rows 0..3; they drain under the qr GEMM ----
    const float* srcA = (lane < 32) ? rec : edge;
    const int dloc = (lane * 8) & 255;
    const float* baseA = srcA + (long)(tok0 + wave * 2) * NREC * EMB + dloc;
    const float* baseB = baseA + (long)NREC * EMB;   // token A+1
    float4 a0l = *reinterpret_cast<const float4*>(baseA + 0 * EMB);
    float4 a0h = *reinterpret_cast<const float4*>(baseA + 0 * EMB + 4);
    float4 a1l = *reinterpret_cast<const float4*>(baseA + 1 * EMB);
    float4 a1h = *reinterpret_cast<const float4*>(baseA + 1 * EMB + 4);
    float4 a2l = *reinterpret_cast<const float4*>(baseA + 2 * EMB);
    float4 a2h = *reinterpret_cast<const float4*>(baseA + 2 * EMB + 4);
    float4 a3l = *reinterpret_cast<const float4*>(baseA + 3 * EMB);
    float4 a3h = *reinterpret_cast<const float4*>(baseA + 3 * EMB + 4);
    __syncthreads();                            // B2: qbf ready

    // ---- 1b: qr = q @ Wr  (M=16,K=256,N=512; 4 n-tiles/wave), stored bf16 ----
    {
        f32x4 racc[4] = {};
        #pragma unroll
        for (int kt = 0; kt < 8; ++kt) {
            int kk = kt * 32 + ((lane >> 4) << 3);
            int row = lane & 15;
            bf16x8 a = *reinterpret_cast<const bf16x8*>(qbf + 512 * row + ((kk * 2) ^ ((row & 7) << 4)));
            #pragma unroll
            for (int ntl = 0; ntl < 4; ++ntl) {
                int nt = wave * 4 + ntl;
                bf16x8 b = load_b_tr<USE_FRAG>(wr_frag + ((nt * 8 + kt) * 64 + lane) * 8,
                                               Wr_w, nt * 16 + (lane & 15), kk, TWO_EMB);
                racc[ntl] = __builtin_amdgcn_mfma_f32_16x16x32_bf16(a, b, racc[ntl], 0, 0, 0);
            }
        }
        #pragma unroll
        for (int ntl = 0; ntl < 4; ++ntl) {
            int n = (wave * 4 + ntl) * 16 + (lane & 15);
            #pragma unroll
            for (int i = 0; i < 4; ++i) {
                int row = ((lane >> 4) << 2) + i;
                *reinterpret_cast<unsigned short*>(qrb + row * 1024 + n * 2)
                    = (unsigned short)f2bf_bits(racc[ntl][i]);
            }
        }
    }
    __syncthreads();                            // B3: qrb ready

    // ---- streaming: token A (ring pre-issued), then token B ----
    stream_token(baseA, qrb, xz, wave * 2, lane, a0l, a0h, a1l, a1h, a2l, a2h, a3l, a3h);
    {
        float4 b0l = *reinterpret_cast<const float4*>(baseB + 0 * EMB);
        float4 b0h = *reinterpret_cast<const float4*>(baseB + 0 * EMB + 4);
        float4 b1l = *reinterpret_cast<const float4*>(baseB + 1 * EMB);
        float4 b1h = *reinterpret_cast<const float4*>(baseB + 1 * EMB + 4);
        float4 b2l = *reinterpret_cast<const float4*>(baseB + 2 * EMB);
        float4 b2h = *reinterpret_cast<const float4*>(baseB + 2 * EMB + 4);
        float4 b3l = *reinterpret_cast<const float4*>(baseB + 3 * EMB);
        float4 b3h = *reinterpret_cast<const float4*>(baseB + 3 * EMB + 4);
        stream_token(baseB, qrb, xz, wave * 2 + 1, lane, b0l, b0h, b1l, b1h, b2l, b2h, b3l, b3h);
    }
    __syncthreads();                            // B4: xbar tile ready

    // ---- ph3: out = q + Wv @ xbar + bv  (M=16,K=512,N=256; 2 n-tiles/wave) ----
    {
        f32x4 oacc[2] = {};
        #pragma unroll
        for (int kt = 0; kt < 16; ++kt) {
            int kk = kt * 32 + ((lane >> 4) << 3);
            int row = lane & 15;
            bf16x8 a = *reinterpret_cast<const bf16x8*>(xz + 1024 * row + ((kk * 2) ^ ((row & 7) << 4)));
            #pragma unroll
            for (int ntl = 0; ntl < 2; ++ntl) {
                int nt = wave * 2 + ntl;
                bf16x8 b = load_b_rm<USE_FRAG>(wv_frag + ((nt * 16 + kt) * 64 + lane) * 8,
                                               Wv_w, nt * 16 + (lane & 15), kk, TWO_EMB);
                oacc[ntl] = __builtin_amdgcn_mfma_f32_16x16x32_bf16(a, b, oacc[ntl], 0, 0, 0);
            }
        }
        #pragma unroll
        for (int ntl = 0; ntl < 2; ++ntl) {
            int n = (wave * 2 + ntl) * 16 + (lane & 15);
            float bv = Wv_b[n];
            #pragma unroll
            for (int i = 0; i < 4; ++i) {
                int row = ((lane >> 4) << 2) + i;
                unsigned short qu = *reinterpret_cast<const unsigned short*>(
                    qbf + 512 * row + ((n * 2) ^ ((row & 7) << 4)));
                float qv = __builtin_bit_cast(float, (unsigned int)qu << 16);
                out[(long)(tok0 + row) * OUTD + n] = qv + oacc[ntl][i] + bv;
            }
        }
    }
}

extern "C" void kernel_launch(void* const* d_in, const int* in_sizes, int n_in,
                              void* d_out, int out_size, void* d_ws, size_t ws_size,
                              hipStream_t stream) {
    const float* rec  = (const float*)d_in[0];
    const float* pep  = (const float*)d_in[1];
    const float* edge = (const float*)d_in[2];
    const float* Wp_w = (const float*)d_in[3];
    const float* Wp_b = (const float*)d_in[4];
    const float* Wr_w = (const float*)d_in[5];
    // d_in[6] = Wr_b : irrelevant (softmax shift invariance)
    const float* Wv_w = (const float*)d_in[7];
    const float* Wv_b = (const float*)d_in[8];
    float* out = (float*)d_out;

    const size_t wp_elems = 16 * 8 * 64 * 8;    // 65536
    const size_t wr_elems = 32 * 8 * 64 * 8;    // 131072
    const size_t wv_elems = 16 * 16 * 64 * 8;   // 131072
    const size_t need = (wp_elems + wr_elems + wv_elems) * sizeof(short);
    short* wp_frag = (short*)d_ws;
    short* wr_frag = wp_frag + wp_elems;
    short* wv_frag = wr_frag + wr_elems;

    if (ws_size >= need) {
        prep_wfrag<<<512, 256, 0, stream>>>(Wp_w, Wr_w, Wv_w, wp_frag, wr_frag, wv_frag);
        ga9_fused<1><<<N_TOK / T_BLK, THREADS, 0, stream>>>(rec, pep, edge, Wp_w, Wp_b, Wr_w,
                                                            Wv_w, Wv_b, wp_frag, wr_frag, wv_frag, out);
    } else {
        ga9_fused<0><<<N_TOK / T_BLK, THREADS, 0, stream>>>(rec, pep, edge, Wp_w, Wp_b, Wr_w,
                                                            Wv_w, Wv_b, wp_frag, wr_frag, wv_frag, out);
    }
}